// Round 4
// baseline (3527.253 us; speedup 1.0000x reference)
//
#include <hip/hip_runtime.h>
#include <hip/hip_bf16.h>
#include <math.h>

// Problem constants: T=512, B=64, D=512, H=1024, O=512
constexpr int T = 512;
constexpr int B = 64;
constexpr int D = 512;
constexpr int H = 1024;
constexpr int O = 512;
constexpr int GROUPS = 2;          // independent batch groups (no cross-sync)
constexpr int BG   = B / GROUPS;   // 32 batch rows per group
constexpr int GBLK = 128;          // blocks per group (own the 4096 gate-cols)
constexpr int COLS = 32;           // gate-cols per block
constexpr int KCH  = (D + H) / 8;  // 192 k-chunks of 8 elems

typedef __attribute__((ext_vector_type(8))) __bf16 bf16x8;
typedef __attribute__((ext_vector_type(4))) float  floatx4;

// Round-18 barrier: PACKED flags, one dword per block (512 B per group =
// 8 cache lines). No poller wave, no leader: every compute wave spins
// directly, lane (l&31) watching flag 32s+(l&31) for split s — a scalar
// s_cbranch_vccnz retry until ALL 32 producers of that split arrived.
struct GBar {
    unsigned arr[GBLK];   // flag[gb] = t+1 once block gb finished step t
};

// ---------------------------------------------------------------------------
// W' bf16, strip-major: Wc[strip(128)][kchunk(192)][nl(32)][8].
// Column reorder (round 14, even/odd interleave): within block gb,
//   nl -> s=nl>>4 (strip), jl=(nl>>2)&3, g=nl&3 ; j = gb*8 + 2*jl + s.
// Strip0 = even local j, strip1 = odd local j -> epilogue lane owns the
// ADJACENT pair (j, j+1) -> single 4B h-store.
// k<512 from Wx[g*H+j][k], else Wh[g*H+j][k-512].
// ---------------------------------------------------------------------------
__global__ __launch_bounds__(256) void convert_w(
    const float* __restrict__ Wx, const float* __restrict__ Wh,
    __bf16* __restrict__ Wc)
{
    const int id = blockIdx.x * 256 + threadIdx.x;   // 128*192*32 = 786432
    if (id >= GBLK * KCH * COLS) return;
    const int nl     = id & 31;
    const int kchunk = (id >> 5) % KCH;
    const int strip  = id / (KCH * COLS);
    const int s  = nl >> 4;
    const int jl = (nl >> 2) & 3;
    const int g  = nl & 3;
    const int j  = strip * 8 + 2 * jl + s;
    const int k0 = kchunk * 8;
    const float* src = (k0 < D) ? &Wx[(size_t)(g * H + j) * D + k0]
                                : &Wh[(size_t)(g * H + j) * H + (k0 - D)];
    const float4 a = *(const float4*)src;
    const float4 b = *(const float4*)(src + 4);
    __bf16 t8[8] = {(__bf16)a.x,(__bf16)a.y,(__bf16)a.z,(__bf16)a.w,
                    (__bf16)b.x,(__bf16)b.y,(__bf16)b.z,(__bf16)b.w};
    *(uint4*)&Wc[(size_t)id * 8] = *(uint4*)t8;
}

__global__ __launch_bounds__(256) void make_bias(
    const float* __restrict__ bx, const float* __restrict__ bh,
    float* __restrict__ bias)
{
    const int n = blockIdx.x * 256 + threadIdx.x;
    if (n < 4 * H) {
        const int gbn = n >> 5, nl = n & 31;
        const int s  = nl >> 4;
        const int jl = (nl >> 2) & 3;
        const int g  = nl & 3;
        const int j  = gbn * 8 + 2 * jl + s;
        bias[n] = bx[g * H + j] + bh[g * H + j];
    }
}

// ---------------------------------------------------------------------------
// Persistent LSTM, round 18 = R14 core (identical math) with the wait
// restructured into the h-load asm itself:
//  - flags packed (1 dword/block); lane-distributed spin, scalar retry.
//  - ONE asm block: 4 x { spin(32 flags >= t) ; 8 chunk dwordx4 loads } +
//    final vmcnt(0). All in-flight registers are asm-owned — no compiler
//    copy/spill hazard (the R15-R17 failure mode).
//  - chunk sg needs flags[4sg..4sg+3]; split s gates chunks 8s..8s+7 via
//    flags[32s..32s+31]. Consuming all splits <=> all 128 flags >= t, so
//    R14's WAR store-gate is preserved exactly.
// ---------------------------------------------------------------------------
__global__ __launch_bounds__(128, 1) void lstm_persistent(
    const float* __restrict__ x,     // [T,B,D] fp32
    const __bf16* __restrict__ Wc,   // strip-major bf16 (read once at start)
    const float* __restrict__ bias,  // [4096] reordered
    __bf16* __restrict__ hbufs,      // [GROUPS][2][BG*H] bf16 ping/pong
    float* __restrict__ hfin,        // [B,H] fp32 final h (aliases Wc head)
    GBar* bars)                      // [GROUPS]
{
    __shared__ __attribute__((aligned(16))) __bf16 wlds[KCH * COLS * 8]; // 96 KB

    const int tid   = threadIdx.x;
    const int wid   = tid >> 6;    // wave id == m-tile (16 batch rows), 0..1
    const int lane  = tid & 63;
    const int cm    = lane & 15;
    const int q     = lane >> 4;
    const int group = blockIdx.x >> 7;          // 0..1
    const int gb    = blockIdx.x & 127;         // block within group
    const int n0    = gb * COLS;
    GBar* bar = bars + group;
    __bf16* hb0 = hbufs + (size_t)group * 2 * BG * H;
    __bf16* hb1 = hb0 + BG * H;

    // ---- one-time: W strip -> LDS (6144 x 16B contiguous) ----
    {
        const uint4* wsrc = (const uint4*)(Wc + (size_t)gb * KCH * COLS * 8);
        uint4* wdst = (uint4*)wlds;
        for (int i = tid; i < KCH * COLS; i += 128) wdst[i] = wsrc[i];
    }
    // epilogue mapping: lane owns row_l = wid*16+q*4+(cm&3) and the ADJACENT
    // hidden pair j0 = gb*8 + 2*(cm>>2) (strip0=even), j0+1 (strip1=odd).
    const int p4 = cm & 3;
    const int jl = cm >> 2;
    const int row_l = wid * 16 + q * 4 + p4;     // 0..31 local batch row
    const float4 bias0q = *(const float4*)&bias[n0 + jl * 4];        // strip 0
    const float4 bias1q = *(const float4*)&bias[n0 + 16 + jl * 4];   // strip 1
    float c0 = 0.f, c1 = 0.f;
    __syncthreads();

    // global batch row for this lane's A-fragment position
    const int grow = group * BG + wid * 16 + cm;
    const float* xrow = x + (size_t)grow * D + q * 8;
    const int    hoff = (wid * 16 + cm) * H + q * 8;   // within group h buffer
    const __bf16* wl  = wlds + (q * 32 + cm) * 8;
    const unsigned* fa = bar->arr + (lane & 31);       // per-lane flag addr

    floatx4 acc[2][2];   // [col-strip][k-parity]
    float4  xcur[16][2]; // prefetched x_t fragments

    auto loadx = [&](int tt) {
        const float* xr = xrow + (size_t)tt * (B * D);
        #pragma unroll
        for (int s = 0; s < 16; ++s) {
            xcur[s][0] = *(const float4*)(xr + s * 32);
            xcur[s][1] = *(const float4*)(xr + s * 32 + 4);
        }
    };
    auto xmfma = [&]() {
        acc[0][0] = (floatx4){0,0,0,0}; acc[0][1] = (floatx4){0,0,0,0};
        acc[1][0] = (floatx4){0,0,0,0}; acc[1][1] = (floatx4){0,0,0,0};
        #pragma unroll
        for (int s = 0; s < 16; ++s) {
            const float4 a0 = xcur[s][0], a1 = xcur[s][1];
            const bf16x8 af = {(__bf16)a0.x,(__bf16)a0.y,(__bf16)a0.z,(__bf16)a0.w,
                               (__bf16)a1.x,(__bf16)a1.y,(__bf16)a1.z,(__bf16)a1.w};
            const bf16x8 b0 = *(const bf16x8*)(wl + s * 1024);
            const bf16x8 b1 = *(const bf16x8*)(wl + s * 1024 + 128);
            acc[0][s & 1] = __builtin_amdgcn_mfma_f32_16x16x32_bf16(af, b0, acc[0][s & 1], 0, 0, 0);
            acc[1][s & 1] = __builtin_amdgcn_mfma_f32_16x16x32_bf16(af, b1, acc[1][s & 1], 0, 0, 0);
        }
    };

    // 4x4 transpose across lane-quads: in V[r] = C[row q*4+r][gate p4],
    // out V[r] = C[row q*4+p4][gate r].   (R13-verified butterfly)
    auto quadT = [&](float v[4]) {
        float w0 = __shfl_xor(v[1], 1), w1 = __shfl_xor(v[0], 1);
        float w2 = __shfl_xor(v[3], 1), w3 = __shfl_xor(v[2], 1);
        if (p4 & 1) { v[0] = w0; v[2] = w2; } else { v[1] = w1; v[3] = w3; }
        w0 = __shfl_xor(v[2], 2); w1 = __shfl_xor(v[3], 2);
        w2 = __shfl_xor(v[0], 2); w3 = __shfl_xor(v[1], 2);
        if (p4 & 2) { v[0] = w0; v[1] = w1; } else { v[2] = w2; v[3] = w3; }
    };

    loadx(0);
    xmfma();

    for (int t = 0; t < T; ++t) {
        const __bf16* hcur = (t & 1) ? hb1 : hb0;
        __bf16*       hnxt = (t & 1) ? hb0 : hb1;

        // ---- h-part: 4 splits x { spin(32 flags>=t) ; 8 chunk loads },
        //      all inside ONE asm block; final vmcnt(0) validates outputs.
        //      Spin waits are scalar branches (vccnz = any lane not ready).
        //      Per-split vmcnt(0) after the flag load also drains prior
        //      h-loads — free, since vmem retires in-order and they were
        //      issued earlier with the same latency class. ----
        {
            const __bf16* hbase = hcur + hoff;   // per-lane, 16B aligned
            uint4 hv[32];
            unsigned ftmp;
            asm volatile(
                // split 0: flags[0..31] -> chunks 0..7
                "1: global_load_dword %[f], %[fa], off sc0 sc1\n\t"
                "s_waitcnt vmcnt(0)\n\t"
                "v_cmp_gt_i32 vcc, %[tt], %[f]\n\t"
                "s_cbranch_vccnz 1b\n\t"
                "global_load_dwordx4 %[h0], %[hb], off sc0 sc1\n\t"
                "global_load_dwordx4 %[h1], %[hb], off offset:64 sc0 sc1\n\t"
                "global_load_dwordx4 %[h2], %[hb], off offset:128 sc0 sc1\n\t"
                "global_load_dwordx4 %[h3], %[hb], off offset:192 sc0 sc1\n\t"
                "global_load_dwordx4 %[h4], %[hb], off offset:256 sc0 sc1\n\t"
                "global_load_dwordx4 %[h5], %[hb], off offset:320 sc0 sc1\n\t"
                "global_load_dwordx4 %[h6], %[hb], off offset:384 sc0 sc1\n\t"
                "global_load_dwordx4 %[h7], %[hb], off offset:448 sc0 sc1\n\t"
                // split 1: flags[32..63] -> chunks 8..15
                "1: global_load_dword %[f], %[fa], off offset:128 sc0 sc1\n\t"
                "s_waitcnt vmcnt(0)\n\t"
                "v_cmp_gt_i32 vcc, %[tt], %[f]\n\t"
                "s_cbranch_vccnz 1b\n\t"
                "global_load_dwordx4 %[h8], %[hb], off offset:512 sc0 sc1\n\t"
                "global_load_dwordx4 %[h9], %[hb], off offset:576 sc0 sc1\n\t"
                "global_load_dwordx4 %[h10], %[hb], off offset:640 sc0 sc1\n\t"
                "global_load_dwordx4 %[h11], %[hb], off offset:704 sc0 sc1\n\t"
                "global_load_dwordx4 %[h12], %[hb], off offset:768 sc0 sc1\n\t"
                "global_load_dwordx4 %[h13], %[hb], off offset:832 sc0 sc1\n\t"
                "global_load_dwordx4 %[h14], %[hb], off offset:896 sc0 sc1\n\t"
                "global_load_dwordx4 %[h15], %[hb], off offset:960 sc0 sc1\n\t"
                // split 2: flags[64..95] -> chunks 16..23
                "1: global_load_dword %[f], %[fa], off offset:256 sc0 sc1\n\t"
                "s_waitcnt vmcnt(0)\n\t"
                "v_cmp_gt_i32 vcc, %[tt], %[f]\n\t"
                "s_cbranch_vccnz 1b\n\t"
                "global_load_dwordx4 %[h16], %[hb], off offset:1024 sc0 sc1\n\t"
                "global_load_dwordx4 %[h17], %[hb], off offset:1088 sc0 sc1\n\t"
                "global_load_dwordx4 %[h18], %[hb], off offset:1152 sc0 sc1\n\t"
                "global_load_dwordx4 %[h19], %[hb], off offset:1216 sc0 sc1\n\t"
                "global_load_dwordx4 %[h20], %[hb], off offset:1280 sc0 sc1\n\t"
                "global_load_dwordx4 %[h21], %[hb], off offset:1344 sc0 sc1\n\t"
                "global_load_dwordx4 %[h22], %[hb], off offset:1408 sc0 sc1\n\t"
                "global_load_dwordx4 %[h23], %[hb], off offset:1472 sc0 sc1\n\t"
                // split 3: flags[96..127] -> chunks 24..31
                "1: global_load_dword %[f], %[fa], off offset:384 sc0 sc1\n\t"
                "s_waitcnt vmcnt(0)\n\t"
                "v_cmp_gt_i32 vcc, %[tt], %[f]\n\t"
                "s_cbranch_vccnz 1b\n\t"
                "global_load_dwordx4 %[h24], %[hb], off offset:1536 sc0 sc1\n\t"
                "global_load_dwordx4 %[h25], %[hb], off offset:1600 sc0 sc1\n\t"
                "global_load_dwordx4 %[h26], %[hb], off offset:1664 sc0 sc1\n\t"
                "global_load_dwordx4 %[h27], %[hb], off offset:1728 sc0 sc1\n\t"
                "global_load_dwordx4 %[h28], %[hb], off offset:1792 sc0 sc1\n\t"
                "global_load_dwordx4 %[h29], %[hb], off offset:1856 sc0 sc1\n\t"
                "global_load_dwordx4 %[h30], %[hb], off offset:1920 sc0 sc1\n\t"
                "global_load_dwordx4 %[h31], %[hb], off offset:1984 sc0 sc1\n\t"
                "s_waitcnt vmcnt(0)"
                : [h0]"=&v"(hv[0]),  [h1]"=&v"(hv[1]),  [h2]"=&v"(hv[2]),  [h3]"=&v"(hv[3]),
                  [h4]"=&v"(hv[4]),  [h5]"=&v"(hv[5]),  [h6]"=&v"(hv[6]),  [h7]"=&v"(hv[7]),
                  [h8]"=&v"(hv[8]),  [h9]"=&v"(hv[9]),  [h10]"=&v"(hv[10]), [h11]"=&v"(hv[11]),
                  [h12]"=&v"(hv[12]), [h13]"=&v"(hv[13]), [h14]"=&v"(hv[14]), [h15]"=&v"(hv[15]),
                  [h16]"=&v"(hv[16]), [h17]"=&v"(hv[17]), [h18]"=&v"(hv[18]), [h19]"=&v"(hv[19]),
                  [h20]"=&v"(hv[20]), [h21]"=&v"(hv[21]), [h22]"=&v"(hv[22]), [h23]"=&v"(hv[23]),
                  [h24]"=&v"(hv[24]), [h25]"=&v"(hv[25]), [h26]"=&v"(hv[26]), [h27]"=&v"(hv[27]),
                  [h28]"=&v"(hv[28]), [h29]"=&v"(hv[29]), [h30]"=&v"(hv[30]), [h31]"=&v"(hv[31]),
                  [f]"=&v"(ftmp)
                : [hb]"v"(hbase), [fa]"v"(fa), [tt]"v"(t)
                : "memory", "vcc");
            #pragma unroll
            for (int sg = 0; sg < 32; ++sg) {
                union { uint4 u; bf16x8 v; } hf; hf.u = hv[sg];
                const bf16x8 b0 = *(const bf16x8*)(wl + 16384 + sg * 1024);
                const bf16x8 b1 = *(const bf16x8*)(wl + 16384 + sg * 1024 + 128);
                acc[0][sg & 1] = __builtin_amdgcn_mfma_f32_16x16x32_bf16(hf.v, b0, acc[0][sg & 1], 0, 0, 0);
                acc[1][sg & 1] = __builtin_amdgcn_mfma_f32_16x16x32_bf16(hf.v, b1, acc[1][sg & 1], 0, 0, 0);
            }
        }
        const floatx4 av0 = acc[0][0] + acc[0][1];
        const floatx4 av1 = acc[1][0] + acc[1][1];

        // ---- in-register quad transpose ----
        float g0v[4] = {av0.x, av0.y, av0.z, av0.w};
        float g1v[4] = {av1.x, av1.y, av1.z, av1.w};
        quadT(g0v);
        quadT(g1v);

        // ---- prefetch x for t+1 (RTT hides under the cell update) ----
        if (t + 1 < T) loadx(t + 1);

        // ---- fused cell update: lane owns (row_l, j0) and (row_l, j0+1) ----
        const float i0 = 1.f / (1.f + expf(-(g0v[0] + bias0q.x)));
        const float f0 = 1.f / (1.f + expf(-(g0v[1] + bias0q.y)));
        const float o0 = 1.f / (1.f + expf(-(g0v[2] + bias0q.z)));
        const float t0 = tanhf(g0v[3] + bias0q.w);
        const float i1 = 1.f / (1.f + expf(-(g1v[0] + bias1q.x)));
        const float f1 = 1.f / (1.f + expf(-(g1v[1] + bias1q.y)));
        const float o1 = 1.f / (1.f + expf(-(g1v[2] + bias1q.z)));
        const float t1 = tanhf(g1v[3] + bias1q.w);
        c0 = f0 * c0 + i0 * t0;
        c1 = f1 * c1 + i1 * t1;
        const float hv0 = o0 * tanhf(c0);
        const float hv1 = o1 * tanhf(c1);
        const int j0 = gb * 8 + 2 * jl;      // even local j; pair (j0, j0+1)
        const int hi = row_l * H + j0;
        union { __bf16 h2[2]; unsigned u; } hp;
        hp.h2[0] = (__bf16)hv0; hp.h2[1] = (__bf16)hv1;
        __hip_atomic_store((unsigned*)&hnxt[hi], hp.u, __ATOMIC_RELAXED,
                           __HIP_MEMORY_SCOPE_AGENT);   // one 4B write-through
        if (t == T - 1) {
            const int gr = group * BG + row_l;
            hfin[gr * H + j0]     = hv0;
            hfin[gr * H + j0 + 1] = hv1;
        }

        __syncthreads();  // drain all threads' h stores (vmcnt0) before arrive

        // ---- arrive: leader stores the block's packed flag ----
        if (tid == 0)
            __hip_atomic_store(&bar->arr[gb], (unsigned)(t + 1),
                               __ATOMIC_RELAXED, __HIP_MEMORY_SCOPE_AGENT);

        // ---- x MFMAs for t+1 in the propagation shadow ----
        if (t + 1 < T) xmfma();
    }
}

// out[b,o] = h[b,:] . Why[o,:] + bhy[o]
__global__ __launch_bounds__(256) void out_gemm(
    const float* __restrict__ h, const float* __restrict__ Why,
    const float* __restrict__ bhy, float* __restrict__ out)
{
    const int idx = blockIdx.x * 256 + threadIdx.x;
    if (idx >= B * O) return;
    const int b = idx / O;
    const int o = idx % O;
    const float4* hv = (const float4*)&h[(size_t)b * H];
    const float4* wv = (const float4*)&Why[(size_t)o * H];
    float s = 0.f;
    #pragma unroll 4
    for (int k = 0; k < H / 4; ++k) {
        const float4 a = hv[k];
        const float4 w = wv[k];
        s += a.x * w.x + a.y * w.y + a.z * w.z + a.w * w.w;
    }
    out[idx] = s + bhy[o];
}

extern "C" void kernel_launch(void* const* d_in, const int* in_sizes, int n_in,
                              void* d_out, int out_size, void* d_ws, size_t ws_size,
                              hipStream_t stream) {
    const float* x   = (const float*)d_in[0];
    const float* Wx  = (const float*)d_in[1];
    const float* bx  = (const float*)d_in[2];
    const float* Wh  = (const float*)d_in[3];
    const float* bh  = (const float*)d_in[4];
    const float* Why = (const float*)d_in[5];
    const float* bhy = (const float*)d_in[6];
    float* out = (float*)d_out;

    // ws layout (~12.86 MB total, <= proven 12.90 MB):
    // Wc 12,582,912 | bias 16,384 @12,582,912 | hbufs 262,144 @12,599,296
    // bars 2 x 512 @12,861,440 (packed flags)
    // hfin (256 KB fp32) aliases Wc[0:262144) — Wc only read during the
    // one-time LDS stage, 511 barriers before any t=T-1 write. Safe.
    char* ws = (char*)d_ws;
    __bf16* Wc    = (__bf16*)ws;
    float*  bias  = (float*)(ws + 12582912);
    __bf16* hbufs = (__bf16*)(ws + 12599296);   // [2][2][BG*H] = 256 KB
    GBar*   bars  = (GBar*)  (ws + 12861440);   // 2 x 512 B (packed flags)
    float*  hfin  = (float*)ws;

    (void)hipMemsetAsync(ws + 12599296, 0, 262144 + 2 * sizeof(GBar), stream);
    convert_w<<<3072, 256, 0, stream>>>(Wx, Wh, Wc);
    make_bias<<<16, 256, 0, stream>>>(bx, bh, bias);

    lstm_persistent<<<GROUPS * GBLK, 128, 0, stream>>>(x, Wc, bias, hbufs,
                                                       hfin, bars);

    out_gemm<<<(B * O + 255) / 256, 256, 0, stream>>>(hfin, Why, bhy, out);
}

// Round 5
// 3197.650 us; speedup vs baseline: 1.1031x; 1.1031x over previous
//
#include <hip/hip_runtime.h>
#include <hip/hip_bf16.h>
#include <math.h>

// Problem constants: T=512, B=64, D=512, H=1024, O=512
constexpr int T = 512;
constexpr int B = 64;
constexpr int D = 512;
constexpr int H = 1024;
constexpr int O = 512;
constexpr int GROUPS = 2;          // independent batch groups (no cross-sync)
constexpr int BG   = B / GROUPS;   // 32 batch rows per group
constexpr int GBLK = 128;          // blocks per group (own the 4096 gate-cols)
constexpr int COLS = 32;           // gate-cols per block
constexpr int KCH  = (D + H) / 8;  // 192 k-chunks of 8 elems

typedef __attribute__((ext_vector_type(8))) __bf16 bf16x8;
typedef __attribute__((ext_vector_type(4))) float  floatx4;

// Round-19 barrier: PACKED flags, one dword per block (512 B per group =
// 4 cache lines). Every compute wave spins directly: lane l watches flags
// 2l and 2l+1; scalar retry until ALL 128 producers arrived; then the
// whole 64 KB h-burst issues back-to-back with ONE final vmcnt(0).
struct GBar {
    unsigned arr[GBLK];   // flag[gb] = t+1 once block gb finished step t
};

// ---------------------------------------------------------------------------
// W' bf16, strip-major: Wc[strip(128)][kchunk(192)][nl(32)][8].
// Column reorder (round 14, even/odd interleave): within block gb,
//   nl -> s=nl>>4 (strip), jl=(nl>>2)&3, g=nl&3 ; j = gb*8 + 2*jl + s.
// Strip0 = even local j, strip1 = odd local j -> epilogue lane owns the
// ADJACENT pair (j, j+1) -> single 4B h-store.
// k<512 from Wx[g*H+j][k], else Wh[g*H+j][k-512].
// ---------------------------------------------------------------------------
__global__ __launch_bounds__(256) void convert_w(
    const float* __restrict__ Wx, const float* __restrict__ Wh,
    __bf16* __restrict__ Wc)
{
    const int id = blockIdx.x * 256 + threadIdx.x;   // 128*192*32 = 786432
    if (id >= GBLK * KCH * COLS) return;
    const int nl     = id & 31;
    const int kchunk = (id >> 5) % KCH;
    const int strip  = id / (KCH * COLS);
    const int s  = nl >> 4;
    const int jl = (nl >> 2) & 3;
    const int g  = nl & 3;
    const int j  = strip * 8 + 2 * jl + s;
    const int k0 = kchunk * 8;
    const float* src = (k0 < D) ? &Wx[(size_t)(g * H + j) * D + k0]
                                : &Wh[(size_t)(g * H + j) * H + (k0 - D)];
    const float4 a = *(const float4*)src;
    const float4 b = *(const float4*)(src + 4);
    __bf16 t8[8] = {(__bf16)a.x,(__bf16)a.y,(__bf16)a.z,(__bf16)a.w,
                    (__bf16)b.x,(__bf16)b.y,(__bf16)b.z,(__bf16)b.w};
    *(uint4*)&Wc[(size_t)id * 8] = *(uint4*)t8;
}

__global__ __launch_bounds__(256) void make_bias(
    const float* __restrict__ bx, const float* __restrict__ bh,
    float* __restrict__ bias)
{
    const int n = blockIdx.x * 256 + threadIdx.x;
    if (n < 4 * H) {
        const int gbn = n >> 5, nl = n & 31;
        const int s  = nl >> 4;
        const int jl = (nl >> 2) & 3;
        const int g  = nl & 3;
        const int j  = gbn * 8 + 2 * jl + s;
        bias[n] = bx[g * H + j] + bh[g * H + j];
    }
}

// ---------------------------------------------------------------------------
// Persistent LSTM, round 19 = R14 core (identical math, single burst) with:
//  - PACKED flags (1 dword/block): poll transactions drop ~30x vs R14's
//    128-padded-line scan (4 lines/group instead of 128).
//  - in-wave spin: both compute waves poll directly (lane l watches flags
//    2l, 2l+1; s_sleep backoff) -> removes the wave0-poll -> syncthreads
//    observe hop (~1 RTT off the critical path).
//  - spin + all 32 h-loads + final vmcnt(0) in ONE asm block, no
//    intermediate drains (R18's 4-way serialization removed).
//  All-flags spin is the WAR store-gate exactly as in R14.
// ---------------------------------------------------------------------------
__global__ __launch_bounds__(128, 1) void lstm_persistent(
    const float* __restrict__ x,     // [T,B,D] fp32
    const __bf16* __restrict__ Wc,   // strip-major bf16 (read once at start)
    const float* __restrict__ bias,  // [4096] reordered
    __bf16* __restrict__ hbufs,      // [GROUPS][2][BG*H] bf16 ping/pong
    float* __restrict__ hfin,        // [B,H] fp32 final h (aliases Wc head)
    GBar* bars)                      // [GROUPS]
{
    __shared__ __attribute__((aligned(16))) __bf16 wlds[KCH * COLS * 8]; // 96 KB

    const int tid   = threadIdx.x;
    const int wid   = tid >> 6;    // wave id == m-tile (16 batch rows), 0..1
    const int lane  = tid & 63;
    const int cm    = lane & 15;
    const int q     = lane >> 4;
    const int group = blockIdx.x >> 7;          // 0..1
    const int gb    = blockIdx.x & 127;         // block within group
    const int n0    = gb * COLS;
    GBar* bar = bars + group;
    __bf16* hb0 = hbufs + (size_t)group * 2 * BG * H;
    __bf16* hb1 = hb0 + BG * H;

    // ---- one-time: W strip -> LDS (6144 x 16B contiguous) ----
    {
        const uint4* wsrc = (const uint4*)(Wc + (size_t)gb * KCH * COLS * 8);
        uint4* wdst = (uint4*)wlds;
        for (int i = tid; i < KCH * COLS; i += 128) wdst[i] = wsrc[i];
    }
    // epilogue mapping: lane owns row_l = wid*16+q*4+(cm&3) and the ADJACENT
    // hidden pair j0 = gb*8 + 2*(cm>>2) (strip0=even), j0+1 (strip1=odd).
    const int p4 = cm & 3;
    const int jl = cm >> 2;
    const int row_l = wid * 16 + q * 4 + p4;     // 0..31 local batch row
    const float4 bias0q = *(const float4*)&bias[n0 + jl * 4];        // strip 0
    const float4 bias1q = *(const float4*)&bias[n0 + 16 + jl * 4];   // strip 1
    float c0 = 0.f, c1 = 0.f;
    __syncthreads();

    // global batch row for this lane's A-fragment position
    const int grow = group * BG + wid * 16 + cm;
    const float* xrow = x + (size_t)grow * D + q * 8;
    const int    hoff = (wid * 16 + cm) * H + q * 8;   // within group h buffer
    const __bf16* wl  = wlds + (q * 32 + cm) * 8;
    const unsigned* fa = bar->arr + 2 * lane;          // lane watches 2 flags

    floatx4 acc[2][2];   // [col-strip][k-parity]
    float4  xcur[16][2]; // prefetched x_t fragments

    auto loadx = [&](int tt) {
        const float* xr = xrow + (size_t)tt * (B * D);
        #pragma unroll
        for (int s = 0; s < 16; ++s) {
            xcur[s][0] = *(const float4*)(xr + s * 32);
            xcur[s][1] = *(const float4*)(xr + s * 32 + 4);
        }
    };
    auto xmfma = [&]() {
        acc[0][0] = (floatx4){0,0,0,0}; acc[0][1] = (floatx4){0,0,0,0};
        acc[1][0] = (floatx4){0,0,0,0}; acc[1][1] = (floatx4){0,0,0,0};
        #pragma unroll
        for (int s = 0; s < 16; ++s) {
            const float4 a0 = xcur[s][0], a1 = xcur[s][1];
            const bf16x8 af = {(__bf16)a0.x,(__bf16)a0.y,(__bf16)a0.z,(__bf16)a0.w,
                               (__bf16)a1.x,(__bf16)a1.y,(__bf16)a1.z,(__bf16)a1.w};
            const bf16x8 b0 = *(const bf16x8*)(wl + s * 1024);
            const bf16x8 b1 = *(const bf16x8*)(wl + s * 1024 + 128);
            acc[0][s & 1] = __builtin_amdgcn_mfma_f32_16x16x32_bf16(af, b0, acc[0][s & 1], 0, 0, 0);
            acc[1][s & 1] = __builtin_amdgcn_mfma_f32_16x16x32_bf16(af, b1, acc[1][s & 1], 0, 0, 0);
        }
    };

    // 4x4 transpose across lane-quads: in V[r] = C[row q*4+r][gate p4],
    // out V[r] = C[row q*4+p4][gate r].   (R13-verified butterfly)
    auto quadT = [&](float v[4]) {
        float w0 = __shfl_xor(v[1], 1), w1 = __shfl_xor(v[0], 1);
        float w2 = __shfl_xor(v[3], 1), w3 = __shfl_xor(v[2], 1);
        if (p4 & 1) { v[0] = w0; v[2] = w2; } else { v[1] = w1; v[3] = w3; }
        w0 = __shfl_xor(v[2], 2); w1 = __shfl_xor(v[3], 2);
        w2 = __shfl_xor(v[0], 2); w3 = __shfl_xor(v[1], 2);
        if (p4 & 2) { v[0] = w0; v[1] = w1; } else { v[2] = w2; v[3] = w3; }
    };

    loadx(0);
    xmfma();

    for (int t = 0; t < T; ++t) {
        const __bf16* hcur = (t & 1) ? hb1 : hb0;
        __bf16*       hnxt = (t & 1) ? hb0 : hb1;

        // ---- h-part: one spin (all 128 packed flags >= t; s_sleep backoff)
        //      then the full 32-chunk burst, ONE final vmcnt(0). Everything
        //      in a single asm block: outputs are valid at block end, so the
        //      compiler may freely use them afterwards (no R15-17 hazard,
        //      no R18 serialization). ----
        {
            const __bf16* hbase = hcur + hoff;   // per-lane, 16B aligned
            uint4 hv[32];
            unsigned f0t, f1t;
            asm volatile(
                "1: global_load_dword %[f0], %[fa], off sc0 sc1\n\t"
                "global_load_dword %[f1], %[fa], off offset:4 sc0 sc1\n\t"
                "s_waitcnt vmcnt(0)\n\t"
                "v_min_i32 %[f0], %[f0], %[f1]\n\t"
                "v_cmp_gt_i32 vcc, %[tt], %[f0]\n\t"
                "s_cbranch_vccz 2f\n\t"
                "s_sleep 1\n\t"
                "s_branch 1b\n\t"
                "2: global_load_dwordx4 %[h0], %[hb], off sc0 sc1\n\t"
                "global_load_dwordx4 %[h1], %[hb], off offset:64 sc0 sc1\n\t"
                "global_load_dwordx4 %[h2], %[hb], off offset:128 sc0 sc1\n\t"
                "global_load_dwordx4 %[h3], %[hb], off offset:192 sc0 sc1\n\t"
                "global_load_dwordx4 %[h4], %[hb], off offset:256 sc0 sc1\n\t"
                "global_load_dwordx4 %[h5], %[hb], off offset:320 sc0 sc1\n\t"
                "global_load_dwordx4 %[h6], %[hb], off offset:384 sc0 sc1\n\t"
                "global_load_dwordx4 %[h7], %[hb], off offset:448 sc0 sc1\n\t"
                "global_load_dwordx4 %[h8], %[hb], off offset:512 sc0 sc1\n\t"
                "global_load_dwordx4 %[h9], %[hb], off offset:576 sc0 sc1\n\t"
                "global_load_dwordx4 %[h10], %[hb], off offset:640 sc0 sc1\n\t"
                "global_load_dwordx4 %[h11], %[hb], off offset:704 sc0 sc1\n\t"
                "global_load_dwordx4 %[h12], %[hb], off offset:768 sc0 sc1\n\t"
                "global_load_dwordx4 %[h13], %[hb], off offset:832 sc0 sc1\n\t"
                "global_load_dwordx4 %[h14], %[hb], off offset:896 sc0 sc1\n\t"
                "global_load_dwordx4 %[h15], %[hb], off offset:960 sc0 sc1\n\t"
                "global_load_dwordx4 %[h16], %[hb], off offset:1024 sc0 sc1\n\t"
                "global_load_dwordx4 %[h17], %[hb], off offset:1088 sc0 sc1\n\t"
                "global_load_dwordx4 %[h18], %[hb], off offset:1152 sc0 sc1\n\t"
                "global_load_dwordx4 %[h19], %[hb], off offset:1216 sc0 sc1\n\t"
                "global_load_dwordx4 %[h20], %[hb], off offset:1280 sc0 sc1\n\t"
                "global_load_dwordx4 %[h21], %[hb], off offset:1344 sc0 sc1\n\t"
                "global_load_dwordx4 %[h22], %[hb], off offset:1408 sc0 sc1\n\t"
                "global_load_dwordx4 %[h23], %[hb], off offset:1472 sc0 sc1\n\t"
                "global_load_dwordx4 %[h24], %[hb], off offset:1536 sc0 sc1\n\t"
                "global_load_dwordx4 %[h25], %[hb], off offset:1600 sc0 sc1\n\t"
                "global_load_dwordx4 %[h26], %[hb], off offset:1664 sc0 sc1\n\t"
                "global_load_dwordx4 %[h27], %[hb], off offset:1728 sc0 sc1\n\t"
                "global_load_dwordx4 %[h28], %[hb], off offset:1792 sc0 sc1\n\t"
                "global_load_dwordx4 %[h29], %[hb], off offset:1856 sc0 sc1\n\t"
                "global_load_dwordx4 %[h30], %[hb], off offset:1920 sc0 sc1\n\t"
                "global_load_dwordx4 %[h31], %[hb], off offset:1984 sc0 sc1\n\t"
                "s_waitcnt vmcnt(0)"
                : [h0]"=&v"(hv[0]),  [h1]"=&v"(hv[1]),  [h2]"=&v"(hv[2]),  [h3]"=&v"(hv[3]),
                  [h4]"=&v"(hv[4]),  [h5]"=&v"(hv[5]),  [h6]"=&v"(hv[6]),  [h7]"=&v"(hv[7]),
                  [h8]"=&v"(hv[8]),  [h9]"=&v"(hv[9]),  [h10]"=&v"(hv[10]), [h11]"=&v"(hv[11]),
                  [h12]"=&v"(hv[12]), [h13]"=&v"(hv[13]), [h14]"=&v"(hv[14]), [h15]"=&v"(hv[15]),
                  [h16]"=&v"(hv[16]), [h17]"=&v"(hv[17]), [h18]"=&v"(hv[18]), [h19]"=&v"(hv[19]),
                  [h20]"=&v"(hv[20]), [h21]"=&v"(hv[21]), [h22]"=&v"(hv[22]), [h23]"=&v"(hv[23]),
                  [h24]"=&v"(hv[24]), [h25]"=&v"(hv[25]), [h26]"=&v"(hv[26]), [h27]"=&v"(hv[27]),
                  [h28]"=&v"(hv[28]), [h29]"=&v"(hv[29]), [h30]"=&v"(hv[30]), [h31]"=&v"(hv[31]),
                  [f0]"=&v"(f0t), [f1]"=&v"(f1t)
                : [hb]"v"(hbase), [fa]"v"(fa), [tt]"v"(t)
                : "memory", "vcc");
            #pragma unroll
            for (int sg = 0; sg < 32; ++sg) {
                union { uint4 u; bf16x8 v; } hf; hf.u = hv[sg];
                const bf16x8 b0 = *(const bf16x8*)(wl + 16384 + sg * 1024);
                const bf16x8 b1 = *(const bf16x8*)(wl + 16384 + sg * 1024 + 128);
                acc[0][sg & 1] = __builtin_amdgcn_mfma_f32_16x16x32_bf16(hf.v, b0, acc[0][sg & 1], 0, 0, 0);
                acc[1][sg & 1] = __builtin_amdgcn_mfma_f32_16x16x32_bf16(hf.v, b1, acc[1][sg & 1], 0, 0, 0);
            }
        }
        const floatx4 av0 = acc[0][0] + acc[0][1];
        const floatx4 av1 = acc[1][0] + acc[1][1];

        // ---- in-register quad transpose ----
        float g0v[4] = {av0.x, av0.y, av0.z, av0.w};
        float g1v[4] = {av1.x, av1.y, av1.z, av1.w};
        quadT(g0v);
        quadT(g1v);

        // ---- prefetch x for t+1 (RTT hides under the cell update) ----
        if (t + 1 < T) loadx(t + 1);

        // ---- fused cell update: lane owns (row_l, j0) and (row_l, j0+1) ----
        const float i0 = 1.f / (1.f + expf(-(g0v[0] + bias0q.x)));
        const float f0 = 1.f / (1.f + expf(-(g0v[1] + bias0q.y)));
        const float o0 = 1.f / (1.f + expf(-(g0v[2] + bias0q.z)));
        const float t0 = tanhf(g0v[3] + bias0q.w);
        const float i1 = 1.f / (1.f + expf(-(g1v[0] + bias1q.x)));
        const float f1 = 1.f / (1.f + expf(-(g1v[1] + bias1q.y)));
        const float o1 = 1.f / (1.f + expf(-(g1v[2] + bias1q.z)));
        const float t1 = tanhf(g1v[3] + bias1q.w);
        c0 = f0 * c0 + i0 * t0;
        c1 = f1 * c1 + i1 * t1;
        const float hv0 = o0 * tanhf(c0);
        const float hv1 = o1 * tanhf(c1);
        const int j0 = gb * 8 + 2 * jl;      // even local j; pair (j0, j0+1)
        const int hi = row_l * H + j0;
        union { __bf16 h2[2]; unsigned u; } hp;
        hp.h2[0] = (__bf16)hv0; hp.h2[1] = (__bf16)hv1;
        __hip_atomic_store((unsigned*)&hnxt[hi], hp.u, __ATOMIC_RELAXED,
                           __HIP_MEMORY_SCOPE_AGENT);   // one 4B write-through
        if (t == T - 1) {
            const int gr = group * BG + row_l;
            hfin[gr * H + j0]     = hv0;
            hfin[gr * H + j0 + 1] = hv1;
        }

        __syncthreads();  // drain all threads' h stores (vmcnt0) before arrive

        // ---- arrive: leader stores the block's packed flag ----
        if (tid == 0)
            __hip_atomic_store(&bar->arr[gb], (unsigned)(t + 1),
                               __ATOMIC_RELAXED, __HIP_MEMORY_SCOPE_AGENT);

        // ---- x MFMAs for t+1 in the propagation shadow ----
        if (t + 1 < T) xmfma();
    }
}

// out[b,o] = h[b,:] . Why[o,:] + bhy[o]
__global__ __launch_bounds__(256) void out_gemm(
    const float* __restrict__ h, const float* __restrict__ Why,
    const float* __restrict__ bhy, float* __restrict__ out)
{
    const int idx = blockIdx.x * 256 + threadIdx.x;
    if (idx >= B * O) return;
    const int b = idx / O;
    const int o = idx % O;
    const float4* hv = (const float4*)&h[(size_t)b * H];
    const float4* wv = (const float4*)&Why[(size_t)o * H];
    float s = 0.f;
    #pragma unroll 4
    for (int k = 0; k < H / 4; ++k) {
        const float4 a = hv[k];
        const float4 w = wv[k];
        s += a.x * w.x + a.y * w.y + a.z * w.z + a.w * w.w;
    }
    out[idx] = s + bhy[o];
}

extern "C" void kernel_launch(void* const* d_in, const int* in_sizes, int n_in,
                              void* d_out, int out_size, void* d_ws, size_t ws_size,
                              hipStream_t stream) {
    const float* x   = (const float*)d_in[0];
    const float* Wx  = (const float*)d_in[1];
    const float* bx  = (const float*)d_in[2];
    const float* Wh  = (const float*)d_in[3];
    const float* bh  = (const float*)d_in[4];
    const float* Why = (const float*)d_in[5];
    const float* bhy = (const float*)d_in[6];
    float* out = (float*)d_out;

    // ws layout (~12.86 MB total, <= proven 12.90 MB):
    // Wc 12,582,912 | bias 16,384 @12,582,912 | hbufs 262,144 @12,599,296
    // bars 2 x 512 @12,861,440 (packed flags)
    // hfin (256 KB fp32) aliases Wc[0:262144) — Wc only read during the
    // one-time LDS stage, 511 barriers before any t=T-1 write. Safe.
    char* ws = (char*)d_ws;
    __bf16* Wc    = (__bf16*)ws;
    float*  bias  = (float*)(ws + 12582912);
    __bf16* hbufs = (__bf16*)(ws + 12599296);   // [2][2][BG*H] = 256 KB
    GBar*   bars  = (GBar*)  (ws + 12861440);   // 2 x 512 B (packed flags)
    float*  hfin  = (float*)ws;

    (void)hipMemsetAsync(ws + 12599296, 0, 262144 + 2 * sizeof(GBar), stream);
    convert_w<<<3072, 256, 0, stream>>>(Wx, Wh, Wc);
    make_bias<<<16, 256, 0, stream>>>(bx, bh, bias);

    lstm_persistent<<<GROUPS * GBLK, 128, 0, stream>>>(x, Wc, bias, hbufs,
                                                       hfin, bars);

    out_gemm<<<(B * O + 255) / 256, 256, 0, stream>>>(hfin, Why, bhy, out);
}